// Round 1
// baseline (545.247 us; speedup 1.0000x reference)
//
#include <hip/hip_runtime.h>

// Problem constants (match reference)
#define Tn 4
#define Bn 512
#define Gn 16
#define Nn 256   // Gn*Gn
#define Dn 32
#define PDF 33   // f32 LDS tile pad (conflict-free: bank=(33c+d)%32=(c+d)%32)
#define PDH 34   // bf16 LDS tile pad (bank=(17c+d/2)%32, 17 odd -> permutation)

#define THRESH_C 0.5f
#define EPS_OBJ 1e-8f
#define EPS_POOL 1e-6f
#define ZCMW 5.0f
#define NEGBIG -1e30f

__device__ __forceinline__ float bf16_dec(unsigned short u) {
    return __uint_as_float(((unsigned int)u) << 16);
}
__device__ __forceinline__ unsigned short bf16_enc(float f) {
    unsigned int u = __float_as_uint(f);
    u += 0x7FFFu + ((u >> 16) & 1u);   // round-to-nearest-even
    return (unsigned short)(u >> 16);
}

// ws layout: [0]=z_what_loss [1]=z_pres_loss [2]=pool_loss [3]=objects_loss [4]=n_obj
__global__ __launch_bounds__(256, 2) void fused_losses(
    const float* __restrict__ z_what,
    const float* __restrict__ z_pres_prob,
    const float* __restrict__ z_pres,
    float* __restrict__ ws)
{
    __shared__ float s_z1[Nn * PDF];            // raw z_what[t+1] tile (f32)
    __shared__ unsigned short s_zw0[Nn * PDH];  // |z_what[t]|*p0 tile (bf16)
    __shared__ float s_n1[Nn];                  // ||z1[cell]||
    __shared__ float s_p1[Nn];                  // p1[cell]

    const int tid = threadIdx.x;                // cell index 0..255
    const int t = blockIdx.x / Bn;              // 0..T-2
    const int b = blockIdx.x - t * Bn;

    const size_t cellbase0 = ((size_t)t * Bn + b) * Nn;          // (t,b) cell base
    const size_t cellbase1 = cellbase0 + (size_t)Bn * Nn;        // (t+1,b)

    const float p0 = z_pres_prob[cellbase0 + tid];
    const float p1 = z_pres_prob[cellbase1 + tid];
    s_p1[tid] = p1;

    // Load own cell's D=32 vectors for t and t+1 (8 x float4 each)
    const float4* g0 = (const float4*)(z_what + (cellbase0 + tid) * Dn);
    const float4* g1 = (const float4*)(z_what + (cellbase1 + tid) * Dn);
    float a0[Dn], a1[Dn];
    #pragma unroll
    for (int k = 0; k < 8; ++k) {
        float4 v0 = g0[k];
        float4 v1 = g1[k];
        a0[4*k+0] = v0.x; a0[4*k+1] = v0.y; a0[4*k+2] = v0.z; a0[4*k+3] = v0.w;
        a1[4*k+0] = v1.x; a1[4*k+1] = v1.y; a1[4*k+2] = v1.z; a1[4*k+3] = v1.w;
    }

    float zwl_acc = 0.f, n0sq = 0.f, n1sq = 0.f;
    #pragma unroll
    for (int d = 0; d < Dn; ++d) {
        float df = a1[d] - a0[d];
        zwl_acc += df * df;                 // z_what_loss contribution
        n0sq += a0[d] * a0[d];
        n1sq += a1[d] * a1[d];
        s_z1[tid * PDF + d] = a1[d];
        s_zw0[tid * PDH + d] = bf16_enc(fabsf(a0[d]) * p0);
    }
    const float n0 = sqrtf(n0sq);
    s_n1[tid] = sqrtf(n1sq);
    __syncthreads();

    const int i = tid >> 4, j = tid & 15;

    // ---- pool_loss: 3x3 max-pool (NO wrap, pad=-inf; values>=0 so invalid->0)
    int nidx[8]; bool nval[8];
    {
        int q = 0;
        #pragma unroll
        for (int di = -1; di <= 1; ++di) {
            #pragma unroll
            for (int dj = -1; dj <= 1; ++dj) {
                if (di == 0 && dj == 0) continue;
                int ii = i + di, jj = j + dj;
                bool v = ((unsigned)ii < Gn) && ((unsigned)jj < Gn);
                nidx[q] = v ? (ii * Gn + jj) : tid;
                nval[q] = v;
                ++q;
            }
        }
    }
    float dotp = 0.f, nasq = 0.f, nbsq = 0.f;
    #pragma unroll
    for (int d = 0; d < Dn; ++d) {
        float m = fabsf(a0[d]) * p0;        // own cell (window center)
        #pragma unroll
        for (int q = 0; q < 8; ++q) {
            float v = bf16_dec(s_zw0[nidx[q] * PDH + d]);
            v = nval[q] ? v : 0.f;
            m = fmaxf(m, v);
        }
        float bd = fabsf(a1[d]) * p1;
        dotp += m * bd;
        nasq += m * m;
        nbsq += bd * bd;
    }
    float cosv = dotp / fmaxf(sqrtf(nasq) * sqrtf(nbsq), EPS_POOL);
    float pool_acc = -cosv * 0.5f * (p0 + p1);

    // ---- objects_loss: 9 neighbors WITH wraparound (jnp.roll)
    float sum_sim = 0.f, max_sim = NEGBIG;
    bool anym = false;
    #pragma unroll
    for (int di = -1; di <= 1; ++di) {
        #pragma unroll
        for (int dj = -1; dj <= 1; ++dj) {
            int nb = (((i + di) & 15) * Gn) + ((j + dj) & 15);
            float dotv = 0.f;
            #pragma unroll
            for (int d = 0; d < Dn; ++d) dotv += a0[d] * s_z1[nb * PDF + d];
            float s = dotv / fmaxf(n0 * s_n1[nb], EPS_OBJ);
            bool m = s_p1[nb] > THRESH_C;
            sum_sim += m ? s : 0.f;
            max_sim = fmaxf(max_sim, m ? s : NEGBIG);
            anym = anym || m;
        }
    }
    const bool det = p0 > THRESH_C;
    float obj_acc = (det && anym) ? (sum_sim - ZCMW * max_sim) : 0.f;
    float cnt = det ? 1.f : 0.f;

    // ---- z_pres_loss (blocks with t < T-2 cover output index t)
    float zpl_acc = 0.f;
    if (t < Tn - 2) {
        const size_t zi = cellbase0 + tid;
        float q0 = z_pres[zi];
        float q1 = z_pres[zi + (size_t)Bn * Nn];
        float q2 = z_pres[zi + 2 * (size_t)Bn * Nn];
        float sim = 1.f - (q2 - q0) * (q2 - q0);
        float del = (q2 - q1) * (q2 - q1) + (q0 - q1) * (q0 - q1);
        zpl_acc = sim * del;
    }

    // ---- reduce: wave shuffle, one atomic per wave per accumulator
    float vals[5] = { zwl_acc, zpl_acc, pool_acc, obj_acc, cnt };
    #pragma unroll
    for (int k = 0; k < 5; ++k) {
        float v = vals[k];
        #pragma unroll
        for (int off = 32; off; off >>= 1) v += __shfl_down(v, off);
        if ((tid & 63) == 0) atomicAdd(&ws[k], v);
    }
}

__global__ void finalize(const float* __restrict__ ws,
                         const float* __restrict__ base_losses,
                         const int* __restrict__ gstep,
                         float* __restrict__ out)
{
    float zwl = ws[0], zpl = ws[1], pl = ws[2], ol = ws[3], cnt = ws[4];
    float bl = base_losses[0] + base_losses[1] + base_losses[2] + base_losses[3];
    float scaling = fminf(1.0f, (float)gstep[0] / 300000.0f);
    float loss = bl + zwl * 10.0f + zpl * 1.0f + pl * 1.0f + ol * scaling * 10.0f;
    out[0] = loss;
    out[1] = zwl;
    out[2] = zpl;
    out[3] = pl;
    out[4] = ol;
    out[5] = cnt;
}

extern "C" void kernel_launch(void* const* d_in, const int* in_sizes, int n_in,
                              void* d_out, int out_size, void* d_ws, size_t ws_size,
                              hipStream_t stream) {
    const float* z_what      = (const float*)d_in[0];
    const float* z_pres_prob = (const float*)d_in[1];
    const float* z_pres      = (const float*)d_in[2];
    const float* base_losses = (const float*)d_in[3];
    const int*   gstep       = (const int*)d_in[4];
    float* ws = (float*)d_ws;

    hipMemsetAsync(ws, 0, 5 * sizeof(float), stream);
    fused_losses<<<dim3((Tn - 1) * Bn), dim3(256), 0, stream>>>(z_what, z_pres_prob, z_pres, ws);
    finalize<<<1, 1, 0, stream>>>(ws, base_losses, gstep, (float*)d_out);
}

// Round 2
// 168.521 us; speedup vs baseline: 3.2355x; 3.2355x over previous
//
#include <hip/hip_runtime.h>

// Problem constants (match reference)
#define Tn 4
#define Bn 512
#define Gn 16
#define Nn 256    // Gn*Gn
#define Dn 32
#define PDF 33    // f32 LDS tile pad: bank=(33c+d)%32=(c+d)%32 -> conflict-free
#define PDH 34    // bf16 LDS tile pad: word stride 17 (odd) -> permutation, <=2-way (free)
#define NBLK ((Tn - 1) * Bn)   // 1536 blocks

#define THRESH_C 0.5f
#define EPS_OBJ 1e-8f
#define EPS_POOL 1e-6f
#define ZCMW 5.0f
#define NEGBIG -1e30f

__device__ __forceinline__ float bf16_dec(unsigned short u) {
    return __uint_as_float(((unsigned int)u) << 16);
}
__device__ __forceinline__ unsigned short bf16_enc(float f) {
    unsigned int u = __float_as_uint(f);
    u += 0x7FFFu + ((u >> 16) & 1u);   // round-to-nearest-even
    return (unsigned short)(u >> 16);
}

// d_ws layout: partials[k * NBLK + block], k in 0..4
// k: 0=z_what_loss 1=z_pres_loss 2=pool_loss 3=objects_loss 4=n_obj
__global__ __launch_bounds__(256) void fused_losses(
    const float* __restrict__ z_what,
    const float* __restrict__ z_pres_prob,
    const float* __restrict__ z_pres,
    float* __restrict__ partials)
{
    __shared__ float s_z1[Nn * PDF];            // raw z_what[t+1] tile (f32)
    __shared__ unsigned short s_zw0[Nn * PDH];  // |z_what[t]|*p0 tile (bf16)
    __shared__ float s_n1[Nn];                  // ||z1[cell]||
    __shared__ float s_p1[Nn];                  // p1[cell]
    __shared__ float s_red[4 * 5];              // cross-wave reduction

    const int tid = threadIdx.x;                // cell index 0..255
    const int t = blockIdx.x / Bn;              // 0..T-2
    const int b = blockIdx.x - t * Bn;

    const size_t cellbase0 = ((size_t)t * Bn + b) * Nn;      // (t,b)
    const size_t cellbase1 = cellbase0 + (size_t)Bn * Nn;    // (t+1,b)

    const float p0 = z_pres_prob[cellbase0 + tid];
    const float p1 = z_pres_prob[cellbase1 + tid];
    s_p1[tid] = p1;

    // Load own cell's D=32 vectors; a0 persistent in regs, z1 straight to LDS
    const float4* g0 = (const float4*)(z_what + (cellbase0 + tid) * Dn);
    const float4* g1 = (const float4*)(z_what + (cellbase1 + tid) * Dn);

    float a0[Dn];
    float zwl_acc = 0.f, n0sq = 0.f, n1sq = 0.f;
    #pragma unroll
    for (int k = 0; k < 8; ++k) {
        float4 v0 = g0[k];
        float4 v1 = g1[k];
        float c0[4] = { v0.x, v0.y, v0.z, v0.w };
        float c1[4] = { v1.x, v1.y, v1.z, v1.w };
        #pragma unroll
        for (int c = 0; c < 4; ++c) {
            int d = 4 * k + c;
            float df = c1[c] - c0[c];
            zwl_acc += df * df;
            n0sq += c0[c] * c0[c];
            n1sq += c1[c] * c1[c];
            a0[d] = c0[c];
            s_z1[tid * PDF + d] = c1[c];
            s_zw0[tid * PDH + d] = bf16_enc(fabsf(c0[c]) * p0);
        }
    }
    const float n0 = sqrtf(n0sq);
    s_n1[tid] = sqrtf(n1sq);
    __syncthreads();

    const int i = tid >> 4, j = tid & 15;

    // ---- pool_loss: 3x3 max-pool (NO wrap; pad=-inf, values>=0 so OOB->0)
    int nidx[8]; bool nval[8];
    {
        int q = 0;
        #pragma unroll
        for (int di = -1; di <= 1; ++di) {
            #pragma unroll
            for (int dj = -1; dj <= 1; ++dj) {
                if (di == 0 && dj == 0) continue;
                int ii = i + di, jj = j + dj;
                bool v = ((unsigned)ii < Gn) && ((unsigned)jj < Gn);
                nidx[q] = v ? (ii * Gn + jj) : tid;
                nval[q] = v;
                ++q;
            }
        }
    }
    float dotp = 0.f, nasq = 0.f;
    const float nbsq = n1sq * p1 * p1;          // exact: sum(|z1_d| p1)^2 = p1^2 ||z1||^2
    #pragma unroll
    for (int d = 0; d < Dn; ++d) {
        float m = fabsf(a0[d]) * p0;            // own cell (window center), f32
        #pragma unroll
        for (int q = 0; q < 8; ++q) {
            float v = bf16_dec(s_zw0[nidx[q] * PDH + d]);
            v = nval[q] ? v : 0.f;
            m = fmaxf(m, v);
        }
        float bd = fabsf(s_z1[tid * PDF + d]) * p1;
        dotp += m * bd;
        nasq += m * m;
    }
    float cosv = dotp / fmaxf(sqrtf(nasq) * sqrtf(nbsq), EPS_POOL);
    float pool_acc = -cosv * 0.5f * (p0 + p1);

    // ---- objects_loss: 9 neighbors WITH wraparound (jnp.roll)
    float sum_sim = 0.f, max_sim = NEGBIG;
    bool anym = false;
    #pragma unroll
    for (int di = -1; di <= 1; ++di) {
        #pragma unroll
        for (int dj = -1; dj <= 1; ++dj) {
            int nb = (((i + di) & 15) * Gn) + ((j + dj) & 15);
            float dotv = 0.f;
            #pragma unroll
            for (int d = 0; d < Dn; ++d) dotv += a0[d] * s_z1[nb * PDF + d];
            float s = dotv / fmaxf(n0 * s_n1[nb], EPS_OBJ);
            bool m = s_p1[nb] > THRESH_C;
            sum_sim += m ? s : 0.f;
            max_sim = fmaxf(max_sim, m ? s : NEGBIG);
            anym = anym || m;
        }
    }
    const bool det = p0 > THRESH_C;
    float obj_acc = (det && anym) ? (sum_sim - ZCMW * max_sim) : 0.f;
    float cnt = det ? 1.f : 0.f;

    // ---- z_pres_loss (blocks with t < T-2 cover output index t)
    float zpl_acc = 0.f;
    if (t < Tn - 2) {
        const size_t zi = cellbase0 + tid;
        float q0 = z_pres[zi];
        float q1 = z_pres[zi + (size_t)Bn * Nn];
        float q2 = z_pres[zi + 2 * (size_t)Bn * Nn];
        float sim = 1.f - (q2 - q0) * (q2 - q0);
        float del = (q2 - q1) * (q2 - q1) + (q0 - q1) * (q0 - q1);
        zpl_acc = sim * del;
    }

    // ---- block reduction: wave shuffle -> LDS -> 5 plain stores (NO atomics)
    const int lane = tid & 63, wave = tid >> 6;
    float vals[5] = { zwl_acc, zpl_acc, pool_acc, obj_acc, cnt };
    #pragma unroll
    for (int k = 0; k < 5; ++k) {
        float v = vals[k];
        #pragma unroll
        for (int off = 32; off; off >>= 1) v += __shfl_down(v, off);
        if (lane == 0) s_red[wave * 5 + k] = v;
    }
    __syncthreads();
    if (tid < 5) {
        float v = s_red[tid] + s_red[5 + tid] + s_red[10 + tid] + s_red[15 + tid];
        partials[tid * NBLK + blockIdx.x] = v;
    }
}

__global__ __launch_bounds__(256) void reduce_finalize(
    const float* __restrict__ partials,
    const float* __restrict__ base_losses,
    const int* __restrict__ gstep,
    float* __restrict__ out)
{
    __shared__ float s_red[4 * 5];
    const int tid = threadIdx.x;
    float acc[5] = { 0.f, 0.f, 0.f, 0.f, 0.f };
    for (int idx = tid; idx < NBLK; idx += 256) {
        #pragma unroll
        for (int k = 0; k < 5; ++k) acc[k] += partials[k * NBLK + idx];
    }
    const int lane = tid & 63, wave = tid >> 6;
    #pragma unroll
    for (int k = 0; k < 5; ++k) {
        float v = acc[k];
        #pragma unroll
        for (int off = 32; off; off >>= 1) v += __shfl_down(v, off);
        if (lane == 0) s_red[wave * 5 + k] = v;
    }
    __syncthreads();
    if (tid == 0) {
        float r[5];
        #pragma unroll
        for (int k = 0; k < 5; ++k)
            r[k] = s_red[k] + s_red[5 + k] + s_red[10 + k] + s_red[15 + k];
        float bl = base_losses[0] + base_losses[1] + base_losses[2] + base_losses[3];
        float scaling = fminf(1.0f, (float)gstep[0] / 300000.0f);
        out[0] = bl + r[0] * 10.0f + r[1] + r[2] + r[3] * scaling * 10.0f;
        out[1] = r[0];
        out[2] = r[1];
        out[3] = r[2];
        out[4] = r[3];
        out[5] = r[4];
    }
}

extern "C" void kernel_launch(void* const* d_in, const int* in_sizes, int n_in,
                              void* d_out, int out_size, void* d_ws, size_t ws_size,
                              hipStream_t stream) {
    const float* z_what      = (const float*)d_in[0];
    const float* z_pres_prob = (const float*)d_in[1];
    const float* z_pres      = (const float*)d_in[2];
    const float* base_losses = (const float*)d_in[3];
    const int*   gstep       = (const int*)d_in[4];
    float* partials = (float*)d_ws;   // 5 * NBLK floats = 30 KB

    fused_losses<<<dim3(NBLK), dim3(256), 0, stream>>>(z_what, z_pres_prob, z_pres, partials);
    reduce_finalize<<<1, 256, 0, stream>>>(partials, base_losses, gstep, (float*)d_out);
}

// Round 3
// 153.547 us; speedup vs baseline: 3.5510x; 1.0975x over previous
//
#include <hip/hip_runtime.h>

// Problem constants (match reference)
#define Tn 4
#define Bn 512
#define Gn 16
#define Nn 256               // Gn*Gn
#define Dn 32
#define NBLK ((Tn - 1) * Bn) // 1536 blocks
#define SW 17                // uint stride/cell in bf16 tiles (34 shorts; 17 odd -> conflict-free)

#define THRESH_C 0.5f
#define EPS_OBJ 1e-8f
#define EPS_POOL 1e-6f
#define ZCMW 5.0f
#define NEGBIG -1e30f

__device__ __forceinline__ unsigned short bf16e(float f) {
    unsigned u = __float_as_uint(f);
    u += 0x7FFFu + ((u >> 16) & 1u);     // RNE (monotone: commutes with max)
    return (unsigned short)(u >> 16);
}
__device__ __forceinline__ unsigned bf16pack(float lo, float hi) {
    return (unsigned)bf16e(lo) | ((unsigned)bf16e(hi) << 16);
}
__device__ __forceinline__ float declo(unsigned u) { return __uint_as_float(u << 16); }
__device__ __forceinline__ float dechi(unsigned u) { return __uint_as_float(u & 0xFFFF0000u); }

// ws: partials[5][NBLK] floats, then unsigned ctr.
// k: 0=z_what_loss 1=z_pres_loss 2=pool_loss 3=objects_loss 4=n_obj
__global__ __launch_bounds__(512, 6) void fused_losses(
    const float* __restrict__ z_what,
    const float* __restrict__ z_pres_prob,
    const float* __restrict__ z_pres,
    const float* __restrict__ base_losses,
    const int* __restrict__ gstep,
    float* __restrict__ partials,
    unsigned* __restrict__ ctr,
    float* __restrict__ out)
{
    __shared__ unsigned s_z1[Nn * SW];   // z_what[t+1] as packed bf16 pairs
    __shared__ unsigned s_rm[Nn * SW];   // row-max of |z0|*p0 as packed bf16
    __shared__ float s_n1[Nn];           // exact f32 ||z1[cell]||
    __shared__ float s_p1[Nn];
    __shared__ float s_red[8 * 5];
    __shared__ int s_last;

    const int tid  = threadIdx.x;        // 0..511
    const int cell = tid >> 1;           // 0..255
    const int half = tid & 1;            // which 16 dims
    const int lane = tid & 63;
    const int wave = tid >> 6;
    const int t = blockIdx.x / Bn;
    const int b = blockIdx.x - t * Bn;

    const size_t cb0 = ((size_t)t * Bn + b) * Nn;
    const size_t cb1 = cb0 + (size_t)Bn * Nn;

    const float p0 = z_pres_prob[cb0 + cell];
    const float p1 = z_pres_prob[cb1 + cell];
    if (half == 0) s_p1[cell] = p1;

    const float4* g0 = (const float4*)(z_what + (cb0 + cell) * Dn + half * 16);
    const float4* g1 = (const float4*)(z_what + (cb1 + cell) * Dn + half * 16);

    // Load own 16 dims of z0/z1; z1 -> LDS (bf16) immediately, a0 stays in regs
    float a0[16];
    float zwl_acc = 0.f, n0sq = 0.f, n1sq = 0.f;
    #pragma unroll
    for (int k = 0; k < 4; ++k) {
        float4 v0 = g0[k], v1 = g1[k];
        float c0[4] = { v0.x, v0.y, v0.z, v0.w };
        float c1[4] = { v1.x, v1.y, v1.z, v1.w };
        #pragma unroll
        for (int c = 0; c < 4; ++c) {
            float df = c1[c] - c0[c];
            zwl_acc += df * df;
            n0sq += c0[c] * c0[c];
            n1sq += c1[c] * c1[c];
            a0[4 * k + c] = c0[c];
        }
        s_z1[cell * SW + half * 8 + 2 * k + 0] = bf16pack(c1[0], c1[1]);
        s_z1[cell * SW + half * 8 + 2 * k + 1] = bf16pack(c1[2], c1[3]);
    }
    n0sq += __shfl_xor(n0sq, 1);
    n1sq += __shfl_xor(n1sq, 1);
    const float n0 = sqrtf(n0sq);
    if (half == 0) s_n1[cell] = sqrtf(n1sq);

    const int i = cell >> 4, j = cell & 15;

    // Separable pool, pass 1: row-max of zw0=|z0|*p0 via in-wave shuffles.
    // j+-1 stays within the wave (wave = 2 full rows); edges masked (values>=0 -> 0 ok).
    #pragma unroll
    for (int q = 0; q < 8; ++q) {
        float e0 = fabsf(a0[2 * q])     * p0;
        float e1 = fabsf(a0[2 * q + 1]) * p0;
        float l0 = __shfl(e0, lane - 2), l1 = __shfl(e1, lane - 2);
        float r0 = __shfl(e0, lane + 2), r1 = __shfl(e1, lane + 2);
        if (j == 0)  { l0 = 0.f; l1 = 0.f; }
        if (j == 15) { r0 = 0.f; r1 = 0.f; }
        s_rm[cell * SW + half * 8 + q] =
            bf16pack(fmaxf(e0, fmaxf(l0, r0)), fmaxf(e1, fmaxf(l1, r1)));
    }
    __syncthreads();

    // Pool pass 2: col-max (no wrap) + cosine vs |z1|*p1
    float dotp = 0.f, nasq = 0.f;
    const float nbsq = n1sq * p1 * p1;   // exact: ||(|z1|*p1)||^2
    {
        const int up = cell - Gn, dn = cell + Gn;
        const bool hasU = (i > 0), hasD = (i < Gn - 1);
        #pragma unroll
        for (int q = 0; q < 8; ++q) {
            unsigned mo = s_rm[cell * SW + half * 8 + q];
            float m0 = declo(mo), m1 = dechi(mo);
            if (hasU) {
                unsigned uu = s_rm[up * SW + half * 8 + q];
                m0 = fmaxf(m0, declo(uu)); m1 = fmaxf(m1, dechi(uu));
            }
            if (hasD) {
                unsigned dd = s_rm[dn * SW + half * 8 + q];
                m0 = fmaxf(m0, declo(dd)); m1 = fmaxf(m1, dechi(dd));
            }
            unsigned z = s_z1[cell * SW + half * 8 + q];
            float b0 = fabsf(declo(z)) * p1;
            float b1 = fabsf(dechi(z)) * p1;
            dotp += m0 * b0 + m1 * b1;
            nasq += m0 * m0 + m1 * m1;
        }
    }
    dotp += __shfl_xor(dotp, 1);
    nasq += __shfl_xor(nasq, 1);
    float cosv = dotp / fmaxf(sqrtf(nasq) * sqrtf(nbsq), EPS_POOL);
    float pool_acc = (half == 0) ? (-cosv * 0.5f * (p0 + p1)) : 0.f;

    // objects_loss: 9 wrapped neighbors (jnp.roll)
    float sum_sim = 0.f, max_sim = NEGBIG;
    bool anym = false;
    #pragma unroll
    for (int di = -1; di <= 1; ++di) {
        #pragma unroll
        for (int dj = -1; dj <= 1; ++dj) {
            int nb = (((i + di) & 15) << 4) | ((j + dj) & 15);
            float dp = 0.f;
            #pragma unroll
            for (int q = 0; q < 8; ++q) {
                unsigned z = s_z1[nb * SW + half * 8 + q];
                dp += a0[2 * q] * declo(z) + a0[2 * q + 1] * dechi(z);
            }
            dp += __shfl_xor(dp, 1);
            float s = dp / fmaxf(n0 * s_n1[nb], EPS_OBJ);
            bool m = s_p1[nb] > THRESH_C;
            sum_sim += m ? s : 0.f;
            max_sim = fmaxf(max_sim, m ? s : NEGBIG);
            anym = anym || m;
        }
    }
    const bool det = p0 > THRESH_C;
    float obj_acc = (det && anym && half == 0) ? (sum_sim - ZCMW * max_sim) : 0.f;
    float cnt = (det && half == 0) ? 1.f : 0.f;

    // z_pres_loss (t index covered by blocks with t < T-2)
    float zpl_acc = 0.f;
    if (half == 0 && t < Tn - 2) {
        const size_t zi = cb0 + cell;
        float q0 = z_pres[zi];
        float q1 = z_pres[zi + (size_t)Bn * Nn];
        float q2 = z_pres[zi + 2 * (size_t)Bn * Nn];
        float sim = 1.f - (q2 - q0) * (q2 - q0);
        zpl_acc = sim * ((q2 - q1) * (q2 - q1) + (q0 - q1) * (q0 - q1));
    }

    // Block reduction: wave shuffle -> LDS
    float vals[5] = { zwl_acc, zpl_acc, pool_acc, obj_acc, cnt };
    #pragma unroll
    for (int k = 0; k < 5; ++k) {
        float v = vals[k];
        #pragma unroll
        for (int off = 32; off; off >>= 1) v += __shfl_down(v, off);
        if (lane == 0) s_red[wave * 5 + k] = v;
    }
    __syncthreads();

    // Single-writer release: tid 0 stores the block's 5 partials, fences, counts.
    if (tid == 0) {
        #pragma unroll
        for (int k = 0; k < 5; ++k) {
            float v = 0.f;
            #pragma unroll
            for (int w = 0; w < 8; ++w) v += s_red[w * 5 + k];
            partials[k * NBLK + blockIdx.x] = v;
        }
        __threadfence();                          // release partials device-wide
        unsigned prev = atomicAdd(ctr, 1u);       // device-scope RMW
        s_last = (prev == NBLK - 1) ? 1 : 0;
    }
    __syncthreads();

    // Last block reduces all partials and finalizes (no second kernel launch)
    if (s_last) {
        __threadfence();                          // acquire
        float acc[5] = { 0.f, 0.f, 0.f, 0.f, 0.f };
        for (int idx = tid; idx < NBLK; idx += 512) {
            #pragma unroll
            for (int k = 0; k < 5; ++k) acc[k] += partials[k * NBLK + idx];
        }
        #pragma unroll
        for (int k = 0; k < 5; ++k) {
            float v = acc[k];
            #pragma unroll
            for (int off = 32; off; off >>= 1) v += __shfl_down(v, off);
            if (lane == 0) s_red[wave * 5 + k] = v;
        }
        __syncthreads();
        if (tid == 0) {
            float r[5];
            #pragma unroll
            for (int k = 0; k < 5; ++k) {
                float v = 0.f;
                #pragma unroll
                for (int w = 0; w < 8; ++w) v += s_red[w * 5 + k];
                r[k] = v;
            }
            float bl = base_losses[0] + base_losses[1] + base_losses[2] + base_losses[3];
            float scaling = fminf(1.0f, (float)gstep[0] / 300000.0f);
            out[0] = bl + r[0] * 10.0f + r[1] + r[2] + r[3] * scaling * 10.0f;
            out[1] = r[0];
            out[2] = r[1];
            out[3] = r[2];
            out[4] = r[3];
            out[5] = r[4];
        }
    }
}

extern "C" void kernel_launch(void* const* d_in, const int* in_sizes, int n_in,
                              void* d_out, int out_size, void* d_ws, size_t ws_size,
                              hipStream_t stream) {
    const float* z_what      = (const float*)d_in[0];
    const float* z_pres_prob = (const float*)d_in[1];
    const float* z_pres      = (const float*)d_in[2];
    const float* base_losses = (const float*)d_in[3];
    const int*   gstep       = (const int*)d_in[4];

    float* partials = (float*)d_ws;                       // 5*NBLK floats
    unsigned* ctr   = (unsigned*)(partials + 5 * NBLK);   // 4 bytes

    hipMemsetAsync(ctr, 0, sizeof(unsigned), stream);
    fused_losses<<<dim3(NBLK), dim3(512), 0, stream>>>(
        z_what, z_pres_prob, z_pres, base_losses, gstep,
        partials, ctr, (float*)d_out);
}

// Round 5
// 149.774 us; speedup vs baseline: 3.6405x; 1.0252x over previous
//
#include <hip/hip_runtime.h>

// Problem constants (match reference)
#define Tn 4
#define Bn 512
#define Gn 16
#define Nn 256               // Gn*Gn
#define Dn 32
#define NBLK ((Tn - 1) * Bn) // 1536 blocks
#define SW 17                // uint stride/cell in bf16 tiles (17 odd -> conflict-free b32)

#define THRESH_C 0.5f
#define EPS_POOL 1e-6f
#define ZCMW 5.0f
#define NEGBIG -1e30f

typedef unsigned int uint_t;
typedef __attribute__((ext_vector_type(2))) unsigned short u16x2;

__device__ __forceinline__ unsigned short bf16e(float f) {
    unsigned u = __float_as_uint(f);
    u += 0x7FFFu + ((u >> 16) & 1u);     // RNE (monotone on non-negatives: commutes with max)
    return (unsigned short)(u >> 16);
}
__device__ __forceinline__ uint_t pack_bf16(float lo, float hi) {
    return (uint_t)bf16e(lo) | ((uint_t)bf16e(hi) << 16);
}
__device__ __forceinline__ float declo(uint_t u) { return __uint_as_float(u << 16); }
__device__ __forceinline__ float dechi(uint_t u) { return __uint_as_float(u & 0xFFFF0000u); }
// packed max of two bf16 pairs; valid because all values >= 0 (bf16 order == u16 order)
__device__ __forceinline__ uint_t pkmax(uint_t a, uint_t b) {
    u16x2 r = __builtin_elementwise_max(__builtin_bit_cast(u16x2, a),
                                        __builtin_bit_cast(u16x2, b));
    return __builtin_bit_cast(uint_t, r);
}

// ws: partials[5][NBLK] floats, then unsigned ctr.
// k: 0=z_what_loss 1=z_pres_loss 2=pool_loss 3=objects_loss 4=n_obj
__global__ __launch_bounds__(512, 6) void fused_losses(
    const float* __restrict__ z_what,
    const float* __restrict__ z_pres_prob,
    const float* __restrict__ z_pres,
    const float* __restrict__ base_losses,
    const int* __restrict__ gstep,
    float* __restrict__ partials,
    unsigned* __restrict__ ctr,
    float* __restrict__ out)
{
    __shared__ uint_t s_z1[Nn * SW];   // z_what[t+1], packed bf16 pairs
    __shared__ uint_t s_buf[Nn * SW];  // overlay: e=|z0|*p0, then row-max(e)
    __shared__ float2 s_np[Nn];        // {p1, 1/max(n1,1e-5)}
    __shared__ float s_red[8 * 5];
    __shared__ int s_last;

    const int tid  = threadIdx.x;      // 0..511
    const int cell = tid >> 1;         // 0..255
    const int half = tid & 1;          // which 16 dims
    const int lane = tid & 63;
    const int wave = tid >> 6;
    const int t = blockIdx.x >> 9;     // Bn = 512
    const int b = blockIdx.x & (Bn - 1);

    const size_t cb0 = ((size_t)t * Bn + b) * Nn;
    const size_t cb1 = cb0 + (size_t)Bn * Nn;

    const float p0 = z_pres_prob[cb0 + cell];
    const float p1 = z_pres_prob[cb1 + cell];

    const float4* g0 = (const float4*)(z_what + (cb0 + cell) * Dn + half * 16);
    const float4* g1 = (const float4*)(z_what + (cb1 + cell) * Dn + half * 16);

    // ---- load own 16 dims; a0 (f32) + pz1 (packed bf16) persistent
    float a0[16];
    uint_t pz1[8];
    float zwl_acc = 0.f, n0sq = 0.f, n1sq = 0.f;
    #pragma unroll
    for (int k = 0; k < 4; ++k) {
        float4 v0 = g0[k], v1 = g1[k];
        float c0[4] = { v0.x, v0.y, v0.z, v0.w };
        float c1[4] = { v1.x, v1.y, v1.z, v1.w };
        #pragma unroll
        for (int c = 0; c < 4; ++c) {
            float df = c1[c] - c0[c];
            zwl_acc += df * df;
            n0sq += c0[c] * c0[c];
            n1sq += c1[c] * c1[c];
            a0[4 * k + c] = c0[c];
        }
        pz1[2 * k]     = pack_bf16(c1[0], c1[1]);
        pz1[2 * k + 1] = pack_bf16(c1[2], c1[3]);
    }
    n0sq += __shfl_xor(n0sq, 1);       // xor-1 -> DPP, cheap
    n1sq += __shfl_xor(n1sq, 1);
    const float n0 = sqrtf(n0sq);
    const float inv_n0 = 1.0f / fmaxf(n0, 1e-5f);

    uint_t* myz   = &s_z1[cell * SW + half * 8];
    uint_t* mybuf = &s_buf[cell * SW + half * 8];

    uint_t pe[8];
    #pragma unroll
    for (int q = 0; q < 8; ++q) {
        myz[q] = pz1[q];
        uint_t e = pack_bf16(fabsf(a0[2 * q]) * p0, fabsf(a0[2 * q + 1]) * p0);
        pe[q] = e;
        mybuf[q] = e;
    }
    if (half == 0) {
        float n1 = sqrtf(n1sq);
        s_np[cell] = make_float2(p1, 1.0f / fmaxf(n1, 1e-5f));
    }
    __syncthreads();   // A: e + z1 + np visible

    const int i = cell >> 4, j = cell & 15;

    // ---- row-max of e (j-1, j, j+1; edges clamp to own cell: max(x,x)=x)
    uint_t rm[8];
    {
        const int cl = (j > 0)  ? cell - 1 : cell;
        const int cr = (j < 15) ? cell + 1 : cell;
        const uint_t* le = &s_buf[cl * SW + half * 8];
        const uint_t* re = &s_buf[cr * SW + half * 8];
        #pragma unroll
        for (int q = 0; q < 8; ++q)
            rm[q] = pkmax(pkmax(pe[q], le[q]), re[q]);
    }
    __syncthreads();   // B: all e reads done before overwrite
    #pragma unroll
    for (int q = 0; q < 8; ++q) mybuf[q] = rm[q];
    __syncthreads();   // C: row-max visible

    // ---- col-max (i-1, i, i+1; edges clamp) + pool cosine vs |z1|*p1
    float dotp = 0.f, nasq = 0.f;
    {
        const int cu = (i > 0)  ? cell - Gn : cell;
        const int cd = (i < 15) ? cell + Gn : cell;
        const uint_t* ub = &s_buf[cu * SW + half * 8];
        const uint_t* db = &s_buf[cd * SW + half * 8];
        #pragma unroll
        for (int q = 0; q < 8; ++q) {
            uint_t m = pkmax(pkmax(rm[q], ub[q]), db[q]);
            float m0 = declo(m), m1 = dechi(m);
            uint_t z = pz1[q];
            float b0 = fabsf(declo(z)), b1 = fabsf(dechi(z));
            dotp += m0 * b0 + m1 * b1;    // * p1 hoisted below
            nasq += m0 * m0 + m1 * m1;
        }
    }
    dotp += __shfl_xor(dotp, 1);
    nasq += __shfl_xor(nasq, 1);
    dotp *= p1;
    const float nbsq = n1sq * p1 * p1;    // exact ||(|z1|*p1)||^2
    float cosv = dotp / fmaxf(sqrtf(nasq) * sqrtf(nbsq), EPS_POOL);
    float pool_acc = (half == 0) ? (-cosv * 0.5f * (p0 + p1)) : 0.f;

    // ---- objects_loss: 9 wrapped neighbors (jnp.roll), reciprocal-normalized
    float sum_sim = 0.f, max_sim = NEGBIG;
    bool anym = false;
    #pragma unroll
    for (int di = -1; di <= 1; ++di) {
        #pragma unroll
        for (int dj = -1; dj <= 1; ++dj) {
            const int nb = (((i + di) & 15) << 4) | ((j + dj) & 15);
            const uint_t* zz = &s_z1[nb * SW + half * 8];
            float dp = 0.f;
            #pragma unroll
            for (int q = 0; q < 8; ++q) {
                uint_t z = zz[q];
                dp += a0[2 * q] * declo(z) + a0[2 * q + 1] * dechi(z);
            }
            dp += __shfl_xor(dp, 1);
            float2 np = s_np[nb];
            float s = dp * inv_n0 * np.y;
            bool m = np.x > THRESH_C;
            sum_sim += m ? s : 0.f;
            max_sim = fmaxf(max_sim, m ? s : NEGBIG);
            anym = anym || m;
        }
    }
    const bool det = p0 > THRESH_C;
    float obj_acc = (det && anym && half == 0) ? (sum_sim - ZCMW * max_sim) : 0.f;
    float cnt = (det && half == 0) ? 1.f : 0.f;

    // ---- z_pres_loss (t index covered by blocks with t < T-2)
    float zpl_acc = 0.f;
    if (half == 0 && t < Tn - 2) {
        const size_t zi = cb0 + cell;
        float q0 = z_pres[zi];
        float q1 = z_pres[zi + (size_t)Bn * Nn];
        float q2 = z_pres[zi + 2 * (size_t)Bn * Nn];
        float sim = 1.f - (q2 - q0) * (q2 - q0);
        zpl_acc = sim * ((q2 - q1) * (q2 - q1) + (q0 - q1) * (q0 - q1));
    }

    // ---- block reduction: wave shuffle -> LDS
    float vals[5] = { zwl_acc, zpl_acc, pool_acc, obj_acc, cnt };
    #pragma unroll
    for (int k = 0; k < 5; ++k) {
        float v = vals[k];
        #pragma unroll
        for (int off = 32; off; off >>= 1) v += __shfl_down(v, off);
        if (lane == 0) s_red[wave * 5 + k] = v;
    }
    __syncthreads();

    if (tid == 0) {
        #pragma unroll
        for (int k = 0; k < 5; ++k) {
            float v = 0.f;
            #pragma unroll
            for (int w = 0; w < 8; ++w) v += s_red[w * 5 + k];
            partials[k * NBLK + blockIdx.x] = v;
        }
        __threadfence();                    // release partials
        unsigned prev = atomicAdd(ctr, 1u); // device-scope
        s_last = (prev == NBLK - 1) ? 1 : 0;
    }
    __syncthreads();

    // ---- last block reduces all partials and finalizes (no 2nd launch)
    if (s_last) {
        __threadfence();                    // acquire
        float acc[5] = { 0.f, 0.f, 0.f, 0.f, 0.f };
        for (int idx = tid; idx < NBLK; idx += 512) {
            #pragma unroll
            for (int k = 0; k < 5; ++k) acc[k] += partials[k * NBLK + idx];
        }
        #pragma unroll
        for (int k = 0; k < 5; ++k) {
            float v = acc[k];
            #pragma unroll
            for (int off = 32; off; off >>= 1) v += __shfl_down(v, off);
            if (lane == 0) s_red[wave * 5 + k] = v;
        }
        __syncthreads();
        if (tid == 0) {
            float r[5];
            #pragma unroll
            for (int k = 0; k < 5; ++k) {
                float v = 0.f;
                #pragma unroll
                for (int w = 0; w < 8; ++w) v += s_red[w * 5 + k];
                r[k] = v;
            }
            float bl = base_losses[0] + base_losses[1] + base_losses[2] + base_losses[3];
            float scaling = fminf(1.0f, (float)gstep[0] / 300000.0f);
            out[0] = bl + r[0] * 10.0f + r[1] + r[2] + r[3] * scaling * 10.0f;
            out[1] = r[0];
            out[2] = r[1];
            out[3] = r[2];
            out[4] = r[3];
            out[5] = r[4];
        }
    }
}

extern "C" void kernel_launch(void* const* d_in, const int* in_sizes, int n_in,
                              void* d_out, int out_size, void* d_ws, size_t ws_size,
                              hipStream_t stream) {
    const float* z_what      = (const float*)d_in[0];
    const float* z_pres_prob = (const float*)d_in[1];
    const float* z_pres      = (const float*)d_in[2];
    const float* base_losses = (const float*)d_in[3];
    const int*   gstep       = (const int*)d_in[4];

    float* partials = (float*)d_ws;                       // 5*NBLK floats
    unsigned* ctr   = (unsigned*)(partials + 5 * NBLK);   // 4 bytes

    (void)hipMemsetAsync(ctr, 0, sizeof(unsigned), stream);
    fused_losses<<<dim3(NBLK), dim3(512), 0, stream>>>(
        z_what, z_pres_prob, z_pres, base_losses, gstep,
        partials, ctr, (float*)d_out);
}